// Round 10
// baseline (476.808 us; speedup 1.0000x reference)
//
#include <hip/hip_runtime.h>
#include <hip/hip_bf16.h>

// Problem constants
#define BB 8
#define SS 4096
#define DD 2048
#define HH 16
#define HDIM 128
#define LL 16
#define JJ 256           // HH*LL, j = h*16 + l
#define ROWS (BB*SS)     // 32768
#define LN_EPS 1e-5f

typedef __attribute__((ext_vector_type(8))) short short8;
typedef __attribute__((ext_vector_type(4))) float f32x4;

typedef __attribute__((address_space(1))) const unsigned int gu32;
typedef __attribute__((address_space(3))) unsigned int lu32;
__device__ __forceinline__ void async16(const void* g, void* l) {
  __builtin_amdgcn_global_load_lds((gu32*)g, (lu32*)l, 16, 0, 0);
}

__device__ __forceinline__ unsigned short f2bf(float f) {
  unsigned int u = __builtin_bit_cast(unsigned int, f);
  u += 0x7fffu + ((u >> 16) & 1u);        // round-to-nearest-even
  return (unsigned short)(u >> 16);
}
__device__ __forceinline__ float bf2f(unsigned short u) {
  unsigned int v = ((unsigned int)u) << 16;
  return __builtin_bit_cast(float, v);
}

// ---------------------------------------------------------------- q partials: qpart[eb][l][c]
__global__ __launch_bounds__(256) void k_q_part(const float* latents, const float* w_lq, float* qpart) {
  int c  = blockIdx.x * 256 + threadIdx.x;  // 0..2047
  int e0 = blockIdx.y * 64;                 // 32 chunks
  float acc[16];
#pragma unroll
  for (int l = 0; l < 16; ++l) acc[l] = 0.f;
  for (int e = e0; e < e0 + 64; ++e) {
    float w = w_lq[(size_t)e * 2048 + c];
#pragma unroll
    for (int l = 0; l < 16; ++l) acc[l] += latents[l * 2048 + e] * w;
  }
#pragma unroll
  for (int l = 0; l < 16; ++l) qpart[((size_t)blockIdx.y * 16 + l) * 2048 + c] = acc[l];
}

// ---------------------------------------------------------------- 32-partial reduce: out[r][c] = bias[c] + sum_p part[p][r][c]
__global__ __launch_bounds__(256) void k_reduce(const float* part, const float* bias, float* out, int R) {
  int c = blockIdx.x * 256 + threadIdx.x;   // grid.x = 8
  int r = blockIdx.y;                       // grid.y = R
  float s = bias[c];
  for (int p = 0; p < 32; ++p) s += part[((size_t)p * R + r) * 2048 + c];
  out[r * 2048 + c] = s;
}

// ---------------------------------------------------------------- fused LN: h = bf16(LN(x))
__global__ __launch_bounds__(256) void k_lnT(const float* x, const float* ln_g, const float* ln_b,
                                             short* h) {
  int row = blockIdx.x;                     // 0..32767
  int t = threadIdx.x;
  const float4* xr = (const float4*)(x + (size_t)row * 2048);
  float4 v0 = xr[t * 2];
  float4 v1 = xr[t * 2 + 1];
  float s  = v0.x + v0.y + v0.z + v0.w + v1.x + v1.y + v1.z + v1.w;
  float s2 = v0.x*v0.x + v0.y*v0.y + v0.z*v0.z + v0.w*v0.w
           + v1.x*v1.x + v1.y*v1.y + v1.z*v1.z + v1.w*v1.w;
#pragma unroll
  for (int o = 32; o; o >>= 1) { s += __shfl_down(s, o); s2 += __shfl_down(s2, o); }
  __shared__ float red[8];
  int wid = t >> 6;
  if ((t & 63) == 0) { red[wid] = s; red[4 + wid] = s2; }
  __syncthreads();
  float ts  = red[0] + red[1] + red[2] + red[3];
  float ts2 = red[4] + red[5] + red[6] + red[7];
  float mu   = ts * (1.0f / 2048.0f);
  float var  = ts2 * (1.0f / 2048.0f) - mu * mu;
  float rstd = rsqrtf(var + LN_EPS);
  const float4* gp = (const float4*)ln_g;
  const float4* bp = (const float4*)ln_b;
  float4 g0 = gp[t * 2], g1 = gp[t * 2 + 1];
  float4 b0 = bp[t * 2], b1 = bp[t * 2 + 1];
  short8 o;
  o[0] = (short)f2bf((v0.x - mu) * rstd * g0.x + b0.x);
  o[1] = (short)f2bf((v0.y - mu) * rstd * g0.y + b0.y);
  o[2] = (short)f2bf((v0.z - mu) * rstd * g0.z + b0.z);
  o[3] = (short)f2bf((v0.w - mu) * rstd * g0.w + b0.w);
  o[4] = (short)f2bf((v1.x - mu) * rstd * g1.x + b1.x);
  o[5] = (short)f2bf((v1.y - mu) * rstd * g1.y + b1.y);
  o[6] = (short)f2bf((v1.z - mu) * rstd * g1.z + b1.z);
  o[7] = (short)f2bf((v1.w - mu) * rstd * g1.w + b1.w);
  ((short8*)(h + (size_t)row * 2048))[t] = o;
}

// ---------------------------------------------------------------- variant: also emit xbf = bf16(x) (big-ws path)
__global__ __launch_bounds__(256) void k_lnT2(const float* x, const float* ln_g, const float* ln_b,
                                              short* h, short* xbf) {
  int row = blockIdx.x;
  int t = threadIdx.x;
  const float4* xr = (const float4*)(x + (size_t)row * 2048);
  float4 v0 = xr[t * 2];
  float4 v1 = xr[t * 2 + 1];
  float s  = v0.x + v0.y + v0.z + v0.w + v1.x + v1.y + v1.z + v1.w;
  float s2 = v0.x*v0.x + v0.y*v0.y + v0.z*v0.z + v0.w*v0.w
           + v1.x*v1.x + v1.y*v1.y + v1.z*v1.z + v1.w*v1.w;
#pragma unroll
  for (int o = 32; o; o >>= 1) { s += __shfl_down(s, o); s2 += __shfl_down(s2, o); }
  __shared__ float red[8];
  int wid = t >> 6;
  if ((t & 63) == 0) { red[wid] = s; red[4 + wid] = s2; }
  __syncthreads();
  float ts  = red[0] + red[1] + red[2] + red[3];
  float ts2 = red[4] + red[5] + red[6] + red[7];
  float mu   = ts * (1.0f / 2048.0f);
  float var  = ts2 * (1.0f / 2048.0f) - mu * mu;
  float rstd = rsqrtf(var + LN_EPS);
  const float4* gp = (const float4*)ln_g;
  const float4* bp = (const float4*)ln_b;
  float4 g0 = gp[t * 2], g1 = gp[t * 2 + 1];
  float4 b0 = bp[t * 2], b1 = bp[t * 2 + 1];
  short8 o, xo;
  o[0] = (short)f2bf((v0.x - mu) * rstd * g0.x + b0.x);
  o[1] = (short)f2bf((v0.y - mu) * rstd * g0.y + b0.y);
  o[2] = (short)f2bf((v0.z - mu) * rstd * g0.z + b0.z);
  o[3] = (short)f2bf((v0.w - mu) * rstd * g0.w + b0.w);
  o[4] = (short)f2bf((v1.x - mu) * rstd * g1.x + b1.x);
  o[5] = (short)f2bf((v1.y - mu) * rstd * g1.y + b1.y);
  o[6] = (short)f2bf((v1.z - mu) * rstd * g1.z + b1.z);
  o[7] = (short)f2bf((v1.w - mu) * rstd * g1.w + b1.w);
  xo[0] = (short)f2bf(v0.x); xo[1] = (short)f2bf(v0.y);
  xo[2] = (short)f2bf(v0.z); xo[3] = (short)f2bf(v0.w);
  xo[4] = (short)f2bf(v1.x); xo[5] = (short)f2bf(v1.y);
  xo[6] = (short)f2bf(v1.z); xo[7] = (short)f2bf(v1.w);
  ((short8*)(h   + (size_t)row * 2048))[t] = o;
  ((short8*)(xbf + (size_t)row * 2048))[t] = xo;
}

// ---------------------------------------------------------------- Wq_t[j][e]
__global__ __launch_bounds__(256) void k_wq(const float* w_k, const float* q, short* wq_t) {
  int e = blockIdx.x;                       // 0..2047
  __shared__ float wrow[2048];
  for (int i = threadIdx.x; i < 512; i += 256)
    ((float4*)wrow)[i] = ((const float4*)(w_k + (size_t)e * 2048))[i];
  __syncthreads();
  int j = threadIdx.x;
  int h = j >> 4, l = j & 15;
  const float* qrow = q + l * 2048 + h * 128;
  const float* wr = wrow + h * 128;
  float acc = 0.f;
#pragma unroll 8
  for (int d = 0; d < 128; ++d) acc += wr[d] * qrow[d];
  wq_t[(size_t)j * 2048 + e] = (short)f2bf(acc * 0.08838834764831845f);
}

// ---------------------------------------------------------------- scores[b][j][s] (bf16) = Wq_t @ h^T
// + fused per-(row, s-tile) softmax partials
__global__ __launch_bounds__(256, 2) void k_scores(const short* h, const short* wq_t,
                                                   short* scores, float* part_ms) {
  int s0 = blockIdx.x * 256;                // 16 s-tiles
  int j0 = blockIdx.y * 64;                 // 4 j-tiles
  int b  = blockIdx.z;
  __shared__ short lds[2 * 4096 + 2 * 16384];   // A dbuf 2x[64][64], B dbuf 2x[256][64]
  int t = threadIdx.x, lane = t & 63, w = t >> 6;
  f32x4 zero = {0.f, 0.f, 0.f, 0.f};
  f32x4 acc[4][4];
#pragma unroll
  for (int m = 0; m < 4; ++m)
#pragma unroll
    for (int n = 0; n < 4; ++n) acc[m][n] = zero;

  int rsel = t >> 3;
  int kcs  = (t & 7) ^ ((t >> 3) & 7);
  const short* hbase  = h + ((size_t)(b * 4096 + s0)) * 2048;
  const short* wqbase = wq_t + (size_t)j0 * 2048;
  int koff0 = (((lane >> 4)) ^ (lane & 7)) * 8;
  int koff1 = ((4 + (lane >> 4)) ^ (lane & 7)) * 8;

  int cur = 0;
  { // prologue: stage K-step 0 into buf 0
    short* lA = lds;
    short* lB = lds + 8192;
#pragma unroll
    for (int i = 0; i < 8; ++i)
      async16(hbase + (size_t)(i * 32 + rsel) * 2048 + kcs * 8,
              lB + (i * 256 + w * 64) * 8);
#pragma unroll
    for (int i = 0; i < 2; ++i)
      async16(wqbase + (size_t)(i * 32 + rsel) * 2048 + kcs * 8,
              lA + (i * 256 + w * 64) * 8);
  }

  for (int it = 0; it < 32; ++it) {
    if (it < 31) {
      int k0 = (it + 1) * 64;
      short* lA1 = lds + (cur ^ 1) * 4096;
      short* lB1 = lds + 8192 + (cur ^ 1) * 16384;
#pragma unroll
      for (int i = 0; i < 8; ++i)
        async16(hbase + (size_t)(i * 32 + rsel) * 2048 + k0 + kcs * 8,
                lB1 + (i * 256 + w * 64) * 8);
#pragma unroll
      for (int i = 0; i < 2; ++i)
        async16(wqbase + (size_t)(i * 32 + rsel) * 2048 + k0 + kcs * 8,
                lA1 + (i * 256 + w * 64) * 8);
      asm volatile("s_waitcnt vmcnt(10)" ::: "memory");
    } else {
      asm volatile("s_waitcnt vmcnt(0)" ::: "memory");
    }
    __builtin_amdgcn_s_barrier();
    __builtin_amdgcn_sched_barrier(0);
    const short* lA = lds + cur * 4096;
    const short* lB = lds + 8192 + cur * 16384;
#pragma unroll
    for (int kk = 0; kk < 2; ++kk) {
      int ko = kk ? koff1 : koff0;
      short8 afr[4];
#pragma unroll
      for (int m = 0; m < 4; ++m)
        afr[m] = *(const short8*)(lA + (m * 16 + (lane & 15)) * 64 + ko);
#pragma unroll
      for (int n = 0; n < 4; ++n) {
        short8 bfr = *(const short8*)(lB + (w * 64 + n * 16 + (lane & 15)) * 64 + ko);
#pragma unroll
        for (int m = 0; m < 4; ++m)
          acc[m][n] = __builtin_amdgcn_mfma_f32_16x16x32_bf16(afr[m], bfr, acc[m][n], 0, 0, 0);
      }
    }
    __builtin_amdgcn_s_barrier();
    cur ^= 1;
  }

  // ---- epilogue: bf16 store + per-row (max, sum-exp) partials over this 256-s tile
  int hi = lane >> 4, cc = lane & 15;
  __syncthreads();
  float2* msred = (float2*)lds;          // [64 j_local][4 w]
#pragma unroll
  for (int m = 0; m < 4; ++m) {
#pragma unroll
    for (int i = 0; i < 4; ++i) {
      int j = j0 + m * 16 + hi * 4 + i;
      float v[4];
#pragma unroll
      for (int n = 0; n < 4; ++n) {
        unsigned short u = f2bf(acc[m][n][i]);
        scores[((size_t)(b * 256 + j)) * 4096 + s0 + w * 64 + n * 16 + cc] = (short)u;
        v[n] = bf2f(u);
      }
      float mx = fmaxf(fmaxf(v[0], v[1]), fmaxf(v[2], v[3]));
#pragma unroll
      for (int o = 1; o < 16; o <<= 1) mx = fmaxf(mx, __shfl_xor(mx, o));
      float sm = __expf(v[0] - mx) + __expf(v[1] - mx) + __expf(v[2] - mx) + __expf(v[3] - mx);
#pragma unroll
      for (int o = 1; o < 16; o <<= 1) sm += __shfl_xor(sm, o);
      if (cc == 0) msred[(m * 16 + hi * 4 + i) * 4 + w] = make_float2(mx, sm);
    }
  }
  __syncthreads();
  if (t < 64) {
    float2 p0 = msred[t * 4 + 0], p1 = msred[t * 4 + 1];
    float2 p2 = msred[t * 4 + 2], p3 = msred[t * 4 + 3];
    float M = fmaxf(fmaxf(p0.x, p1.x), fmaxf(p2.x, p3.x));
    float S = p0.y * __expf(p0.x - M) + p1.y * __expf(p1.x - M)
            + p2.y * __expf(p2.x - M) + p3.y * __expf(p3.x - M);
    ((float2*)part_ms)[((size_t)(b * 256 + j0 + t)) * 16 + blockIdx.x] = make_float2(M, S);
  }
}

// ---------------------------------------------------------------- combine 16 tile-partials per row
__global__ __launch_bounds__(256) void k_msum(const float* part_ms, float* msum) {
  int row = blockIdx.x * 256 + threadIdx.x;  // 0..2047
  const float2* p = (const float2*)(part_ms + (size_t)row * 32);
  float2 v[16];
  float M = -1e30f;
#pragma unroll
  for (int i = 0; i < 16; ++i) { v[i] = p[i]; M = fmaxf(M, v[i].x); }
  float S = 0.f;
#pragma unroll
  for (int i = 0; i < 16; ++i) S += v[i].y * __expf(v[i].x - M);
  msum[row * 2]     = M;
  msum[row * 2 + 1] = 1.0f / (16.0f * S);
}

// ---------------------------------------------------------------- fused pbar + h contraction:
// Tpart[sp*128 + b*16 + hh][e] = sum_{s in chunk} pbar[hh][s] * h[s][e]
__global__ __launch_bounds__(256) void k_pt(const short* scores, const float* msum,
                                            const short* h, float* Tpart) {
  int sp = blockIdx.x;                      // 0..31 (s-chunks of 128)
  int b  = blockIdx.y;
  int t  = threadIdx.x;
  __shared__ short sc[256 * 128];           // scores chunk [j][s], 64 KB
  __shared__ float lp[16 * 128];            // pbar [h][s], 8 KB
#pragma unroll
  for (int rr = 0; rr < 2; ++rr) {
    int j = rr * 128 + (t >> 1);
    const short8* src = (const short8*)(scores + ((size_t)(b * 256 + j)) * 4096 + sp * 128 + (t & 1) * 64);
    short8* dst = (short8*)(sc + j * 128 + (t & 1) * 64);
#pragma unroll
    for (int i = 0; i < 8; ++i) dst[i] = src[i];
  }
  __syncthreads();
  {
    int s = t & 127, hg = (t >> 7) * 8;
    for (int hh = hg; hh < hg + 8; ++hh) {
      const float* ms = msum + (b * 256 + hh * 16) * 2;
      float accp = 0.f;
#pragma unroll
      for (int l = 0; l < 16; ++l)
        accp += __expf(bf2f((unsigned short)sc[(hh * 16 + l) * 128 + s]) - ms[l * 2]) * ms[l * 2 + 1];
      lp[hh * 128 + s] = accp;
    }
  }
  __syncthreads();
  f32x4 a0[16], a1[16];
#pragma unroll
  for (int hh = 0; hh < 16; ++hh) { a0[hh] = (f32x4){0,0,0,0}; a1[hh] = (f32x4){0,0,0,0}; }
  const short* hb = h + ((size_t)(b * 4096 + sp * 128)) * 2048 + t * 8;
  for (int si = 0; si < 128; ++si) {
    short8 hv8 = *(const short8*)(hb + (size_t)si * 2048);
    float hv[8];
#pragma unroll
    for (int c = 0; c < 8; ++c) hv[c] = bf2f((unsigned short)hv8[c]);
#pragma unroll
    for (int hh = 0; hh < 16; ++hh) {
      float p = lp[hh * 128 + si];
#pragma unroll
      for (int c = 0; c < 4; ++c) { a0[hh][c] += p * hv[c]; a1[hh][c] += p * hv[4 + c]; }
    }
  }
#pragma unroll
  for (int hh = 0; hh < 16; ++hh) {
    float* dst = Tpart + ((size_t)(sp * 128 + b * 16 + hh)) * 2048 + t * 8;
    *(f32x4*)dst = a0[hh];
    *(f32x4*)(dst + 4) = a1[hh];
  }
}

// ---------------------------------------------------------------- Tbar[bh][e] = sum_sp Tpart[sp][bh][e]
__global__ __launch_bounds__(256) void k_tred(const float* Tpart, float* Tbar) {
  int bh = blockIdx.x;                      // 0..127
  int e  = blockIdx.y * 1024 + threadIdx.x;
#pragma unroll
  for (int k = 0; k < 4; ++k, e += 256) {
    float s = 0.f;
#pragma unroll
    for (int p = 0; p < 32; ++p) s += Tpart[((size_t)p * 128 + bh) * 2048 + e];
    Tbar[(size_t)bh * 2048 + e] = s;
  }
}

// ---------------------------------------------------------------- cbar partials over e: part[eb][b][c]
__global__ __launch_bounds__(256) void k_cbar_part(const float* Tbar, const float* w_v, float* part) {
  int c  = blockIdx.x * 256 + threadIdx.x;
  int e0 = blockIdx.y * 64;
  int h  = c >> 7;
  float acc[8];
#pragma unroll
  for (int b = 0; b < 8; ++b) acc[b] = 0.f;
  for (int e = e0; e < e0 + 64; ++e) {
    float wv = w_v[(size_t)e * 2048 + c];
#pragma unroll
    for (int b = 0; b < 8; ++b) acc[b] += Tbar[((size_t)b * 16 + h) * 2048 + e] * wv;
  }
#pragma unroll
  for (int b = 0; b < 8; ++b) part[((size_t)blockIdx.y * 8 + b) * 2048 + c] = acc[b];
}

// ---------------------------------------------------------------- vecmat partials over e: part[eb][b][c]
__global__ __launch_bounds__(256) void k_vecmat_part(const float* vin, const float* W, float* part) {
  int c  = blockIdx.x * 256 + threadIdx.x;
  int e0 = blockIdx.y * 64;
  float acc[8];
#pragma unroll
  for (int b = 0; b < 8; ++b) acc[b] = 0.f;
  for (int e = e0; e < e0 + 64; ++e) {
    float wv = W[(size_t)e * 2048 + c];
#pragma unroll
    for (int b = 0; b < 8; ++b) acc[b] += vin[b * 2048 + e] * wv;
  }
#pragma unroll
  for (int b = 0; b < 8; ++b) part[((size_t)blockIdx.y * 8 + b) * 2048 + c] = acc[b];
}

// ---------------------------------------------------------------- out = x + broadcast(outv)   (fp32 x path)
__global__ __launch_bounds__(256) void k_resid(const float* x, const float* outv, float* out) {
  size_t i4 = (size_t)blockIdx.x * 256 + threadIdx.x;
  size_t total4 = (size_t)ROWS * 512;
  size_t stride = (size_t)gridDim.x * 256;
  for (; i4 < total4; i4 += stride) {
    int b  = (int)(i4 >> 21);               // 4096*512 float4 per batch
    int c4 = (int)(i4 & 511);
    float4 xv = ((const float4*)x)[i4];
    float4 ov = ((const float4*)outv)[b * 512 + c4];
    float4 o;
    o.x = xv.x + ov.x; o.y = xv.y + ov.y;
    o.z = xv.z + ov.z; o.w = xv.w + ov.w;
    ((float4*)out)[i4] = o;
  }
}

// ---------------------------------------------------------------- out = bf16(x) + broadcast(outv)  (big-ws path)
__global__ __launch_bounds__(256) void k_resid_bf(const short* xbf, const float* outv, float* out) {
  size_t i8 = (size_t)blockIdx.x * 256 + threadIdx.x;
  size_t total8 = (size_t)ROWS * 256;       // 8-element groups
  size_t stride = (size_t)gridDim.x * 256;
  for (; i8 < total8; i8 += stride) {
    int b  = (int)(i8 >> 20);               // 4096*256 groups per batch
    int c8 = (int)(i8 & 255);
    short8 xv = ((const short8*)xbf)[i8];
    const float4* ovp = (const float4*)(outv + b * 2048 + c8 * 8);
    float4 o0 = ovp[0], o1 = ovp[1];
    float4 r0, r1;
    r0.x = bf2f((unsigned short)xv[0]) + o0.x;
    r0.y = bf2f((unsigned short)xv[1]) + o0.y;
    r0.z = bf2f((unsigned short)xv[2]) + o0.z;
    r0.w = bf2f((unsigned short)xv[3]) + o0.w;
    r1.x = bf2f((unsigned short)xv[4]) + o1.x;
    r1.y = bf2f((unsigned short)xv[5]) + o1.y;
    r1.z = bf2f((unsigned short)xv[6]) + o1.z;
    r1.w = bf2f((unsigned short)xv[7]) + o1.w;
    ((float4*)out)[i8 * 2]     = r0;
    ((float4*)out)[i8 * 2 + 1] = r1;
  }
}

// ================================================================ launch
extern "C" void kernel_launch(void* const* d_in, const int* in_sizes, int n_in,
                              void* d_out, int out_size, void* d_ws, size_t ws_size,
                              hipStream_t stream) {
  const float* x       = (const float*)d_in[0];
  const float* ln_g    = (const float*)d_in[1];
  const float* ln_b    = (const float*)d_in[2];
  const float* latents = (const float*)d_in[3];
  const float* w_lq    = (const float*)d_in[4];
  const float* b_lq    = (const float*)d_in[5];
  const float* w_k     = (const float*)d_in[6];
  // const float* b_k  = (const float*)d_in[7];   // softmax-invariant, unused
  const float* w_v     = (const float*)d_in[8];
  const float* b_v     = (const float*)d_in[9];
  const float* w_lv    = (const float*)d_in[10];
  const float* b_lv    = (const float*)d_in[11];
  const float* w_out   = (const float*)d_in[12];
  const float* b_out   = (const float*)d_in[13];

  // d_out is fp32 [8,4096,2048] = 268 MB; first ~192 MB doubles as scratch,
  // all dead before k_resid overwrites the full buffer. NO overlaps (Tbar full 1 MB).
  char* base = (char*)d_out;
  short* scores  = (short*)(base);                       //  16,777,216 B (bf16)
  short* h       = (short*)(base + 16777216);            // 134,217,728 B (bf16 LN(x))
  float* Tpart   = (float*)(base + 150994944);           //  33,554,432 B
  float* part_ms = (float*)(base + 184549376);           //     262,144 B
  float* msum    = (float*)(base + 184811520);           //      16,384 B
  float* q       = (float*)(base + 184827904);           //     131,072 B
  short* wq_t    = (short*)(base + 184958976);           //   1,048,576 B
  float* Tbar    = (float*)(base + 186007552);           //   1,048,576 B (full size!)
  float* cbar    = (float*)(base + 187056128);           //      65,536 B
  float* pooled  = (float*)(base + 187121664);           //      65,536 B
  float* part    = (float*)(base + 187187200);           //   4,194,304 B (also q-partials)
  float* outv    = (float*)d_ws;                         //      65,536 B (proven safe in r7)
  float* out     = (float*)d_out;

  // big-ws path: bf16(x) copy lives in d_ws ONLY if the workspace is provably large enough
  bool big_ws = ws_size >= (size_t)67174400;             // 64 KB outv + 64 MB xbf
  short* xbf = (short*)((char*)d_ws + 65536);

  k_q_part     <<<dim3(8, 32), 256, 0, stream>>>(latents, w_lq, part);
  k_reduce     <<<dim3(8, 16), 256, 0, stream>>>(part, b_lq, q, 16);
  if (big_ws) k_lnT2<<<32768, 256, 0, stream>>>(x, ln_g, ln_b, h, xbf);
  else        k_lnT <<<32768, 256, 0, stream>>>(x, ln_g, ln_b, h);
  k_wq         <<<2048, 256, 0, stream>>>(w_k, q, wq_t);
  k_scores     <<<dim3(16, 4, 8), 256, 0, stream>>>(h, wq_t, scores, part_ms);
  k_msum       <<<8, 256, 0, stream>>>(part_ms, msum);
  k_pt         <<<dim3(32, 8), 256, 0, stream>>>(scores, msum, h, Tpart);
  k_tred       <<<dim3(128, 2), 256, 0, stream>>>(Tpart, Tbar);
  k_cbar_part  <<<dim3(8, 32), 256, 0, stream>>>(Tbar, w_v, part);
  k_reduce     <<<dim3(8, 8), 256, 0, stream>>>(part, b_v, cbar, 8);
  k_vecmat_part<<<dim3(8, 32), 256, 0, stream>>>(cbar, w_lv, part);
  k_reduce     <<<dim3(8, 8), 256, 0, stream>>>(part, b_lv, pooled, 8);
  k_vecmat_part<<<dim3(8, 32), 256, 0, stream>>>(pooled, w_out, part);
  k_reduce     <<<dim3(8, 8), 256, 0, stream>>>(part, b_out, outv, 8);
  if (big_ws) k_resid_bf<<<2048, 256, 0, stream>>>(xbf, outv, out);
  else        k_resid   <<<2048, 256, 0, stream>>>(x, outv, out);
}

// Round 11
// 429.349 us; speedup vs baseline: 1.1105x; 1.1105x over previous
//
#include <hip/hip_runtime.h>
#include <hip/hip_bf16.h>

// Problem constants
#define BB 8
#define SS 4096
#define DD 2048
#define HH 16
#define HDIM 128
#define LL 16
#define JJ 256           // HH*LL, j = h*16 + l
#define ROWS (BB*SS)     // 32768
#define LN_EPS 1e-5f

typedef __attribute__((ext_vector_type(8))) short short8;
typedef __attribute__((ext_vector_type(4))) float f32x4;

typedef __attribute__((address_space(1))) const unsigned int gu32;
typedef __attribute__((address_space(3))) unsigned int lu32;
__device__ __forceinline__ void async16(const void* g, void* l) {
  __builtin_amdgcn_global_load_lds((gu32*)g, (lu32*)l, 16, 0, 0);
}

__device__ __forceinline__ unsigned short f2bf(float f) {
  unsigned int u = __builtin_bit_cast(unsigned int, f);
  u += 0x7fffu + ((u >> 16) & 1u);        // round-to-nearest-even
  return (unsigned short)(u >> 16);
}
__device__ __forceinline__ float bf2f(unsigned short u) {
  unsigned int v = ((unsigned int)u) << 16;
  return __builtin_bit_cast(float, v);
}

// ---------------------------------------------------------------- q partials: qpart[eb][l][c]
__global__ __launch_bounds__(256) void k_q_part(const float* latents, const float* w_lq, float* qpart) {
  int c  = blockIdx.x * 256 + threadIdx.x;  // 0..2047
  int e0 = blockIdx.y * 64;                 // 32 chunks
  float acc[16];
#pragma unroll
  for (int l = 0; l < 16; ++l) acc[l] = 0.f;
  for (int e = e0; e < e0 + 64; ++e) {
    float w = w_lq[(size_t)e * 2048 + c];
#pragma unroll
    for (int l = 0; l < 16; ++l) acc[l] += latents[l * 2048 + e] * w;
  }
#pragma unroll
  for (int l = 0; l < 16; ++l) qpart[((size_t)blockIdx.y * 16 + l) * 2048 + c] = acc[l];
}

// ---------------------------------------------------------------- 32-partial reduce: out[r][c] = bias[c] + sum_p part[p][r][c]
__global__ __launch_bounds__(256) void k_reduce(const float* part, const float* bias, float* out, int R) {
  int c = blockIdx.x * 256 + threadIdx.x;   // grid.x = 8
  int r = blockIdx.y;                       // grid.y = R
  float s = bias[c];
  for (int p = 0; p < 32; ++p) s += part[((size_t)p * R + r) * 2048 + c];
  out[r * 2048 + c] = s;
}

// ---------------------------------------------------------------- fused LN: h = bf16(LN(x))
__global__ __launch_bounds__(256) void k_lnT(const float* x, const float* ln_g, const float* ln_b,
                                             short* h) {
  int row = blockIdx.x;                     // 0..32767
  int t = threadIdx.x;
  const float4* xr = (const float4*)(x + (size_t)row * 2048);
  float4 v0 = xr[t * 2];
  float4 v1 = xr[t * 2 + 1];
  float s  = v0.x + v0.y + v0.z + v0.w + v1.x + v1.y + v1.z + v1.w;
  float s2 = v0.x*v0.x + v0.y*v0.y + v0.z*v0.z + v0.w*v0.w
           + v1.x*v1.x + v1.y*v1.y + v1.z*v1.z + v1.w*v1.w;
#pragma unroll
  for (int o = 32; o; o >>= 1) { s += __shfl_down(s, o); s2 += __shfl_down(s2, o); }
  __shared__ float red[8];
  int wid = t >> 6;
  if ((t & 63) == 0) { red[wid] = s; red[4 + wid] = s2; }
  __syncthreads();
  float ts  = red[0] + red[1] + red[2] + red[3];
  float ts2 = red[4] + red[5] + red[6] + red[7];
  float mu   = ts * (1.0f / 2048.0f);
  float var  = ts2 * (1.0f / 2048.0f) - mu * mu;
  float rstd = rsqrtf(var + LN_EPS);
  const float4* gp = (const float4*)ln_g;
  const float4* bp = (const float4*)ln_b;
  float4 g0 = gp[t * 2], g1 = gp[t * 2 + 1];
  float4 b0 = bp[t * 2], b1 = bp[t * 2 + 1];
  short8 o;
  o[0] = (short)f2bf((v0.x - mu) * rstd * g0.x + b0.x);
  o[1] = (short)f2bf((v0.y - mu) * rstd * g0.y + b0.y);
  o[2] = (short)f2bf((v0.z - mu) * rstd * g0.z + b0.z);
  o[3] = (short)f2bf((v0.w - mu) * rstd * g0.w + b0.w);
  o[4] = (short)f2bf((v1.x - mu) * rstd * g1.x + b1.x);
  o[5] = (short)f2bf((v1.y - mu) * rstd * g1.y + b1.y);
  o[6] = (short)f2bf((v1.z - mu) * rstd * g1.z + b1.z);
  o[7] = (short)f2bf((v1.w - mu) * rstd * g1.w + b1.w);
  ((short8*)(h + (size_t)row * 2048))[t] = o;
}

// ---------------------------------------------------------------- Wq_t[j][e]
__global__ __launch_bounds__(256) void k_wq(const float* w_k, const float* q, short* wq_t) {
  int e = blockIdx.x;                       // 0..2047
  __shared__ float wrow[2048];
  for (int i = threadIdx.x; i < 512; i += 256)
    ((float4*)wrow)[i] = ((const float4*)(w_k + (size_t)e * 2048))[i];
  __syncthreads();
  int j = threadIdx.x;
  int h = j >> 4, l = j & 15;
  const float* qrow = q + l * 2048 + h * 128;
  const float* wr = wrow + h * 128;
  float acc = 0.f;
#pragma unroll 8
  for (int d = 0; d < 128; ++d) acc += wr[d] * qrow[d];
  wq_t[(size_t)j * 2048 + e] = (short)f2bf(acc * 0.08838834764831845f);
}

// ---------------------------------------------------------------- scores[b][j][s] (bf16) = Wq_t @ h^T
// + fused per-(row, s-tile) softmax partials
__global__ __launch_bounds__(256, 2) void k_scores(const short* h, const short* wq_t,
                                                   short* scores, float* part_ms) {
  int s0 = blockIdx.x * 256;                // 16 s-tiles
  int j0 = blockIdx.y * 64;                 // 4 j-tiles
  int b  = blockIdx.z;
  __shared__ short lds[2 * 4096 + 2 * 16384];   // A dbuf 2x[64][64], B dbuf 2x[256][64]
  int t = threadIdx.x, lane = t & 63, w = t >> 6;
  f32x4 zero = {0.f, 0.f, 0.f, 0.f};
  f32x4 acc[4][4];
#pragma unroll
  for (int m = 0; m < 4; ++m)
#pragma unroll
    for (int n = 0; n < 4; ++n) acc[m][n] = zero;

  int rsel = t >> 3;
  int kcs  = (t & 7) ^ ((t >> 3) & 7);
  const short* hbase  = h + ((size_t)(b * 4096 + s0)) * 2048;
  const short* wqbase = wq_t + (size_t)j0 * 2048;
  int koff0 = (((lane >> 4)) ^ (lane & 7)) * 8;
  int koff1 = ((4 + (lane >> 4)) ^ (lane & 7)) * 8;

  int cur = 0;
  { // prologue: stage K-step 0 into buf 0
    short* lA = lds;
    short* lB = lds + 8192;
#pragma unroll
    for (int i = 0; i < 8; ++i)
      async16(hbase + (size_t)(i * 32 + rsel) * 2048 + kcs * 8,
              lB + (i * 256 + w * 64) * 8);
#pragma unroll
    for (int i = 0; i < 2; ++i)
      async16(wqbase + (size_t)(i * 32 + rsel) * 2048 + kcs * 8,
              lA + (i * 256 + w * 64) * 8);
  }

  for (int it = 0; it < 32; ++it) {
    if (it < 31) {
      int k0 = (it + 1) * 64;
      short* lA1 = lds + (cur ^ 1) * 4096;
      short* lB1 = lds + 8192 + (cur ^ 1) * 16384;
#pragma unroll
      for (int i = 0; i < 8; ++i)
        async16(hbase + (size_t)(i * 32 + rsel) * 2048 + k0 + kcs * 8,
                lB1 + (i * 256 + w * 64) * 8);
#pragma unroll
      for (int i = 0; i < 2; ++i)
        async16(wqbase + (size_t)(i * 32 + rsel) * 2048 + k0 + kcs * 8,
                lA1 + (i * 256 + w * 64) * 8);
      asm volatile("s_waitcnt vmcnt(10)" ::: "memory");
    } else {
      asm volatile("s_waitcnt vmcnt(0)" ::: "memory");
    }
    __builtin_amdgcn_s_barrier();
    __builtin_amdgcn_sched_barrier(0);
    const short* lA = lds + cur * 4096;
    const short* lB = lds + 8192 + cur * 16384;
#pragma unroll
    for (int kk = 0; kk < 2; ++kk) {
      int ko = kk ? koff1 : koff0;
      short8 afr[4];
#pragma unroll
      for (int m = 0; m < 4; ++m)
        afr[m] = *(const short8*)(lA + (m * 16 + (lane & 15)) * 64 + ko);
#pragma unroll
      for (int n = 0; n < 4; ++n) {
        short8 bfr = *(const short8*)(lB + (w * 64 + n * 16 + (lane & 15)) * 64 + ko);
#pragma unroll
        for (int m = 0; m < 4; ++m)
          acc[m][n] = __builtin_amdgcn_mfma_f32_16x16x32_bf16(afr[m], bfr, acc[m][n], 0, 0, 0);
      }
    }
    __builtin_amdgcn_s_barrier();
    cur ^= 1;
  }

  // ---- epilogue: bf16 store + per-row (max, sum-exp) partials over this 256-s tile
  int hi = lane >> 4, cc = lane & 15;
  __syncthreads();
  float2* msred = (float2*)lds;          // [64 j_local][4 w]
#pragma unroll
  for (int m = 0; m < 4; ++m) {
#pragma unroll
    for (int i = 0; i < 4; ++i) {
      int j = j0 + m * 16 + hi * 4 + i;
      float v[4];
#pragma unroll
      for (int n = 0; n < 4; ++n) {
        unsigned short u = f2bf(acc[m][n][i]);
        scores[((size_t)(b * 256 + j)) * 4096 + s0 + w * 64 + n * 16 + cc] = (short)u;
        v[n] = bf2f(u);
      }
      float mx = fmaxf(fmaxf(v[0], v[1]), fmaxf(v[2], v[3]));
#pragma unroll
      for (int o = 1; o < 16; o <<= 1) mx = fmaxf(mx, __shfl_xor(mx, o));
      float sm = __expf(v[0] - mx) + __expf(v[1] - mx) + __expf(v[2] - mx) + __expf(v[3] - mx);
#pragma unroll
      for (int o = 1; o < 16; o <<= 1) sm += __shfl_xor(sm, o);
      if (cc == 0) msred[(m * 16 + hi * 4 + i) * 4 + w] = make_float2(mx, sm);
    }
  }
  __syncthreads();
  if (t < 64) {
    float2 p0 = msred[t * 4 + 0], p1 = msred[t * 4 + 1];
    float2 p2 = msred[t * 4 + 2], p3 = msred[t * 4 + 3];
    float M = fmaxf(fmaxf(p0.x, p1.x), fmaxf(p2.x, p3.x));
    float S = p0.y * __expf(p0.x - M) + p1.y * __expf(p1.x - M)
            + p2.y * __expf(p2.x - M) + p3.y * __expf(p3.x - M);
    ((float2*)part_ms)[((size_t)(b * 256 + j0 + t)) * 16 + blockIdx.x] = make_float2(M, S);
  }
}

// ---------------------------------------------------------------- fused msum + pbar + h contraction:
// Tpart[sp*128 + b*16 + hh][e] = sum_{s in chunk} pbar[hh][s] * h[s][e]
__global__ __launch_bounds__(256) void k_pt(const short* scores, const float* part_ms,
                                            const short* h, float* Tpart) {
  int sp = blockIdx.x;                      // 0..31 (s-chunks of 128)
  int b  = blockIdx.y;
  int t  = threadIdx.x;
  __shared__ short sc[256 * 128];           // scores chunk [j][s], 64 KB
  __shared__ float lp[16 * 128];            // pbar [h][s], 8 KB
  __shared__ float lms[512];                // per-row (max, inv16sum), 2 KB
  { // per-row softmax combine (row r = t of this b) — same order as old k_msum
    const float2* p = ((const float2*)part_ms) + (size_t)(b * 256 + t) * 16;
    float2 v[16];
    float M = -1e30f;
#pragma unroll
    for (int i = 0; i < 16; ++i) { v[i] = p[i]; M = fmaxf(M, v[i].x); }
    float S = 0.f;
#pragma unroll
    for (int i = 0; i < 16; ++i) S += v[i].y * __expf(v[i].x - M);
    lms[t * 2] = M; lms[t * 2 + 1] = 1.0f / (16.0f * S);
  }
#pragma unroll
  for (int rr = 0; rr < 2; ++rr) {          // stage scores [256 j][128 s]
    int j = rr * 128 + (t >> 1);
    const short8* src = (const short8*)(scores + ((size_t)(b * 256 + j)) * 4096 + sp * 128 + (t & 1) * 64);
    short8* dst = (short8*)(sc + j * 128 + (t & 1) * 64);
#pragma unroll
    for (int i = 0; i < 8; ++i) dst[i] = src[i];
  }
  __syncthreads();
  {
    int s = t & 127, hg = (t >> 7) * 8;
    for (int hh = hg; hh < hg + 8; ++hh) {
      float accp = 0.f;
#pragma unroll
      for (int l = 0; l < 16; ++l) {
        int r = hh * 16 + l;
        accp += __expf(bf2f((unsigned short)sc[r * 128 + s]) - lms[r * 2]) * lms[r * 2 + 1];
      }
      lp[hh * 128 + s] = accp;
    }
  }
  __syncthreads();
  f32x4 a0[16], a1[16];
#pragma unroll
  for (int hh = 0; hh < 16; ++hh) { a0[hh] = (f32x4){0,0,0,0}; a1[hh] = (f32x4){0,0,0,0}; }
  const short* hb = h + ((size_t)(b * 4096 + sp * 128)) * 2048 + t * 8;
  for (int si = 0; si < 128; ++si) {
    short8 hv8 = *(const short8*)(hb + (size_t)si * 2048);
    float hv[8];
#pragma unroll
    for (int c = 0; c < 8; ++c) hv[c] = bf2f((unsigned short)hv8[c]);
#pragma unroll
    for (int hh = 0; hh < 16; ++hh) {
      float p = lp[hh * 128 + si];
#pragma unroll
      for (int c = 0; c < 4; ++c) { a0[hh][c] += p * hv[c]; a1[hh][c] += p * hv[4 + c]; }
    }
  }
#pragma unroll
  for (int hh = 0; hh < 16; ++hh) {
    float* dst = Tpart + ((size_t)(sp * 128 + b * 16 + hh)) * 2048 + t * 8;
    *(f32x4*)dst = a0[hh];
    *(f32x4*)(dst + 4) = a1[hh];
  }
}

// ---------------------------------------------------------------- cbar partials (folds Tpart reduce): part[ey][b][c]
__global__ __launch_bounds__(256) void k_cbar_part(const float* Tpart, const float* w_v, float* part) {
  int t  = threadIdx.x;
  int c  = blockIdx.x * 256 + t;
  int e0 = blockIdx.y * 64;
  __shared__ float tb[2][8][64];            // Tbar slice for this block's 2 h values
  {
    int idx = t * 4;
    int hl = idx >> 9, b = (idx >> 6) & 7, ee = idx & 63;
    int hg = blockIdx.x * 2 + hl;
    f32x4 s = {0.f, 0.f, 0.f, 0.f};
    for (int sp = 0; sp < 32; ++sp) {
      f32x4 v = *(const f32x4*)(Tpart + ((size_t)(sp * 128 + b * 16 + hg)) * 2048 + e0 + ee);
      s += v;
    }
    *(f32x4*)&tb[hl][b][ee] = s;
  }
  __syncthreads();
  int h1 = t >> 7;
  float acc[8];
#pragma unroll
  for (int b = 0; b < 8; ++b) acc[b] = 0.f;
  for (int e = 0; e < 64; ++e) {
    float wv = w_v[(size_t)(e0 + e) * 2048 + c];
#pragma unroll
    for (int b = 0; b < 8; ++b) acc[b] += tb[h1][b][e] * wv;
  }
#pragma unroll
  for (int b = 0; b < 8; ++b) part[((size_t)blockIdx.y * 8 + b) * 2048 + c] = acc[b];
}

// ---------------------------------------------------------------- vecmat partials (folds previous reduce + bias)
__global__ __launch_bounds__(256) void k_vecmat_part(const float* partin, const float* bias,
                                                     const float* W, float* partout) {
  int t  = threadIdx.x;
  int c  = blockIdx.x * 256 + t;
  int e0 = blockIdx.y * 64;
  __shared__ float vin[8][64];
  {
#pragma unroll
    for (int k = 0; k < 2; ++k) {
      int idx = t * 2 + k;
      int b = idx >> 6, ee = idx & 63;
      float s = bias[e0 + ee];
      for (int p = 0; p < 32; ++p) s += partin[((size_t)p * 8 + b) * 2048 + e0 + ee];
      vin[b][ee] = s;
    }
  }
  __syncthreads();
  float acc[8];
#pragma unroll
  for (int b = 0; b < 8; ++b) acc[b] = 0.f;
  for (int e = 0; e < 64; ++e) {
    float wv = W[(size_t)(e0 + e) * 2048 + c];
#pragma unroll
    for (int b = 0; b < 8; ++b) acc[b] += vin[b][e] * wv;
  }
#pragma unroll
  for (int b = 0; b < 8; ++b) partout[((size_t)blockIdx.y * 8 + b) * 2048 + c] = acc[b];
}

// ---------------------------------------------------------------- out = x + broadcast(outv)   (fp32)
__global__ __launch_bounds__(256) void k_resid(const float* x, const float* outv, float* out) {
  size_t i4 = (size_t)blockIdx.x * 256 + threadIdx.x;
  size_t total4 = (size_t)ROWS * 512;
  size_t stride = (size_t)gridDim.x * 256;
  for (; i4 < total4; i4 += stride) {
    int b  = (int)(i4 >> 21);               // 4096*512 float4 per batch
    int c4 = (int)(i4 & 511);
    float4 xv = ((const float4*)x)[i4];
    float4 ov = ((const float4*)outv)[b * 512 + c4];
    float4 o;
    o.x = xv.x + ov.x; o.y = xv.y + ov.y;
    o.z = xv.z + ov.z; o.w = xv.w + ov.w;
    ((float4*)out)[i4] = o;
  }
}

// ================================================================ launch
extern "C" void kernel_launch(void* const* d_in, const int* in_sizes, int n_in,
                              void* d_out, int out_size, void* d_ws, size_t ws_size,
                              hipStream_t stream) {
  const float* x       = (const float*)d_in[0];
  const float* ln_g    = (const float*)d_in[1];
  const float* ln_b    = (const float*)d_in[2];
  const float* latents = (const float*)d_in[3];
  const float* w_lq    = (const float*)d_in[4];
  const float* b_lq    = (const float*)d_in[5];
  const float* w_k     = (const float*)d_in[6];
  // const float* b_k  = (const float*)d_in[7];   // softmax-invariant, unused
  const float* w_v     = (const float*)d_in[8];
  const float* b_v     = (const float*)d_in[9];
  const float* w_lv    = (const float*)d_in[10];
  const float* b_lv    = (const float*)d_in[11];
  const float* w_out   = (const float*)d_in[12];
  const float* b_out   = (const float*)d_in[13];

  // d_out is fp32 [8,4096,2048] = 268 MB; first ~195 MB doubles as scratch, no overlaps,
  // all dead before k_resid (which reads only x and outv) overwrites the full buffer.
  char* base = (char*)d_out;
  short* scores  = (short*)(base);                       //  16,777,216 B (bf16)
  short* h       = (short*)(base + 16777216);            // 134,217,728 B (bf16 LN(x))
  float* Tpart   = (float*)(base + 150994944);           //  33,554,432 B
  float* part_ms = (float*)(base + 184549376);           //     262,144 B
  float* q       = (float*)(base + 184811520);           //     131,072 B
  short* wq_t    = (short*)(base + 184942592);           //   1,048,576 B
  float* qpart   = (float*)(base + 185991168);           //   4,194,304 B
  float* part    = (float*)(base + 190185472);           //   2,097,152 B
  float* part2   = (float*)(base + 192282624);           //   2,097,152 B
  float* outv    = (float*)d_ws;                         //      65,536 B (ws_size ≥ 64 KB proven)
  float* out     = (float*)d_out;

  k_q_part     <<<dim3(8, 32), 256, 0, stream>>>(latents, w_lq, qpart);
  k_reduce     <<<dim3(8, 16), 256, 0, stream>>>(qpart, b_lq, q, 16);
  k_lnT        <<<32768, 256, 0, stream>>>(x, ln_g, ln_b, h);
  k_wq         <<<2048, 256, 0, stream>>>(w_k, q, wq_t);
  k_scores     <<<dim3(16, 4, 8), 256, 0, stream>>>(h, wq_t, scores, part_ms);
  k_pt         <<<dim3(32, 8), 256, 0, stream>>>(scores, part_ms, h, Tpart);
  k_cbar_part  <<<dim3(8, 32), 256, 0, stream>>>(Tpart, w_v, part);
  k_vecmat_part<<<dim3(8, 32), 256, 0, stream>>>(part, b_v, w_lv, part2);
  k_vecmat_part<<<dim3(8, 32), 256, 0, stream>>>(part2, b_lv, w_out, part);
  k_reduce     <<<dim3(8, 8), 256, 0, stream>>>(part, b_out, outv, 8);
  k_resid      <<<2048, 256, 0, stream>>>(x, outv, out);
}

// Round 12
// 421.197 us; speedup vs baseline: 1.1320x; 1.0194x over previous
//
#include <hip/hip_runtime.h>
#include <hip/hip_bf16.h>

// Problem constants
#define BB 8
#define SS 4096
#define DD 2048
#define HH 16
#define HDIM 128
#define LL 16
#define JJ 256           // HH*LL, j = h*16 + l
#define ROWS (BB*SS)     // 32768
#define LN_EPS 1e-5f

typedef __attribute__((ext_vector_type(8))) short short8;
typedef __attribute__((ext_vector_type(4))) float f32x4;

typedef __attribute__((address_space(1))) const unsigned int gu32;
typedef __attribute__((address_space(3))) unsigned int lu32;
__device__ __forceinline__ void async16(const void* g, void* l) {
  __builtin_amdgcn_global_load_lds((gu32*)g, (lu32*)l, 16, 0, 0);
}

__device__ __forceinline__ unsigned short f2bf(float f) {
  unsigned int u = __builtin_bit_cast(unsigned int, f);
  u += 0x7fffu + ((u >> 16) & 1u);        // round-to-nearest-even
  return (unsigned short)(u >> 16);
}
__device__ __forceinline__ float bf2f(unsigned short u) {
  unsigned int v = ((unsigned int)u) << 16;
  return __builtin_bit_cast(float, v);
}

// ---------------------------------------------------------------- q partials: qpart[eb][l][c]
__global__ __launch_bounds__(256) void k_q_part(const float* latents, const float* w_lq, float* qpart) {
  int c  = blockIdx.x * 256 + threadIdx.x;  // 0..2047
  int e0 = blockIdx.y * 64;                 // 32 chunks
  float acc[16];
#pragma unroll
  for (int l = 0; l < 16; ++l) acc[l] = 0.f;
  for (int e = e0; e < e0 + 64; ++e) {
    float w = w_lq[(size_t)e * 2048 + c];
#pragma unroll
    for (int l = 0; l < 16; ++l) acc[l] += latents[l * 2048 + e] * w;
  }
#pragma unroll
  for (int l = 0; l < 16; ++l) qpart[((size_t)blockIdx.y * 16 + l) * 2048 + c] = acc[l];
}

// ---------------------------------------------------------------- 32-partial reduce: out[r][c] = bias[c] + sum_p part[p][r][c]
__global__ __launch_bounds__(256) void k_reduce(const float* part, const float* bias, float* out, int R) {
  int c = blockIdx.x * 256 + threadIdx.x;   // grid.x = 8
  int r = blockIdx.y;                       // grid.y = R
  float s = bias[c];
  for (int p = 0; p < 32; ++p) s += part[((size_t)p * R + r) * 2048 + c];
  out[r * 2048 + c] = s;
}

// ---------------------------------------------------------------- fused LN: h = bf16(LN(x))
__global__ __launch_bounds__(256) void k_lnT(const float* x, const float* ln_g, const float* ln_b,
                                             short* h) {
  int row = blockIdx.x;                     // 0..32767
  int t = threadIdx.x;
  const float4* xr = (const float4*)(x + (size_t)row * 2048);
  float4 v0 = xr[t * 2];
  float4 v1 = xr[t * 2 + 1];
  float s  = v0.x + v0.y + v0.z + v0.w + v1.x + v1.y + v1.z + v1.w;
  float s2 = v0.x*v0.x + v0.y*v0.y + v0.z*v0.z + v0.w*v0.w
           + v1.x*v1.x + v1.y*v1.y + v1.z*v1.z + v1.w*v1.w;
#pragma unroll
  for (int o = 32; o; o >>= 1) { s += __shfl_down(s, o); s2 += __shfl_down(s2, o); }
  __shared__ float red[8];
  int wid = t >> 6;
  if ((t & 63) == 0) { red[wid] = s; red[4 + wid] = s2; }
  __syncthreads();
  float ts  = red[0] + red[1] + red[2] + red[3];
  float ts2 = red[4] + red[5] + red[6] + red[7];
  float mu   = ts * (1.0f / 2048.0f);
  float var  = ts2 * (1.0f / 2048.0f) - mu * mu;
  float rstd = rsqrtf(var + LN_EPS);
  const float4* gp = (const float4*)ln_g;
  const float4* bp = (const float4*)ln_b;
  float4 g0 = gp[t * 2], g1 = gp[t * 2 + 1];
  float4 b0 = bp[t * 2], b1 = bp[t * 2 + 1];
  short8 o;
  o[0] = (short)f2bf((v0.x - mu) * rstd * g0.x + b0.x);
  o[1] = (short)f2bf((v0.y - mu) * rstd * g0.y + b0.y);
  o[2] = (short)f2bf((v0.z - mu) * rstd * g0.z + b0.z);
  o[3] = (short)f2bf((v0.w - mu) * rstd * g0.w + b0.w);
  o[4] = (short)f2bf((v1.x - mu) * rstd * g1.x + b1.x);
  o[5] = (short)f2bf((v1.y - mu) * rstd * g1.y + b1.y);
  o[6] = (short)f2bf((v1.z - mu) * rstd * g1.z + b1.z);
  o[7] = (short)f2bf((v1.w - mu) * rstd * g1.w + b1.w);
  ((short8*)(h + (size_t)row * 2048))[t] = o;
}

// ---------------------------------------------------------------- Wq_t[j][e]
__global__ __launch_bounds__(256) void k_wq(const float* w_k, const float* q, short* wq_t) {
  int e = blockIdx.x;                       // 0..2047
  __shared__ float wrow[2048];
  for (int i = threadIdx.x; i < 512; i += 256)
    ((float4*)wrow)[i] = ((const float4*)(w_k + (size_t)e * 2048))[i];
  __syncthreads();
  int j = threadIdx.x;
  int h = j >> 4, l = j & 15;
  const float* qrow = q + l * 2048 + h * 128;
  const float* wr = wrow + h * 128;
  float acc = 0.f;
#pragma unroll 8
  for (int d = 0; d < 128; ++d) acc += wr[d] * qrow[d];
  wq_t[(size_t)j * 2048 + e] = (short)f2bf(acc * 0.08838834764831845f);
}

// ---------------------------------------------------------------- scores[b][j][s] (bf16) = Wq_t @ h^T
// [64j x 128s] tile, 3-buffer LDS, 2-deep prefetch, counted vmcnt(12).
__global__ __launch_bounds__(256, 2) void k_scores(const short* h, const short* wq_t,
                                                   short* scores, float* part_ms) {
  int s0 = blockIdx.x * 128;                // 32 s-tiles
  int j0 = blockIdx.y * 64;                 // 4 j-tiles
  int b  = blockIdx.z;
  __shared__ short lds[3 * 12288];          // 3 x (A[64][64] 8KB + B[128][64] 16KB) = 72 KB
  int t = threadIdx.x, lane = t & 63, w = t >> 6;
  f32x4 zero = {0.f, 0.f, 0.f, 0.f};
  f32x4 acc[4][2];
#pragma unroll
  for (int m = 0; m < 4; ++m)
#pragma unroll
    for (int n = 0; n < 2; ++n) acc[m][n] = zero;

  int rsel = t >> 3;
  int kcs  = (t & 7) ^ ((t >> 3) & 7);      // src k-chunk for this thread's linear dest slot
  const short* hbase  = h + ((size_t)(b * 4096 + s0)) * 2048;
  const short* wqbase = wq_t + (size_t)j0 * 2048;
  int koff0 = (((lane >> 4)) ^ (lane & 7)) * 8;
  int koff1 = ((4 + (lane >> 4)) ^ (lane & 7)) * 8;

#define STAGE_SC(IT, BUF) { \
    int k0_ = (IT) * 64; \
    short* lA_ = lds + (BUF) * 12288; \
    short* lB_ = lA_ + 4096; \
    _Pragma("unroll") \
    for (int i_ = 0; i_ < 4; ++i_) \
      async16(hbase + (size_t)(i_ * 32 + rsel) * 2048 + k0_ + kcs * 8, lB_ + (i_ * 256 + t) * 8); \
    _Pragma("unroll") \
    for (int i_ = 0; i_ < 2; ++i_) \
      async16(wqbase + (size_t)(i_ * 32 + rsel) * 2048 + k0_ + kcs * 8, lA_ + (i_ * 256 + t) * 8); \
  }

  STAGE_SC(0, 0);
  STAGE_SC(1, 1);
  int cb = 0, sb = 2;
  for (int it = 0; it < 32; ++it) {
    if (it < 30) {
      STAGE_SC(it + 2, sb);
      asm volatile("s_waitcnt vmcnt(12)" ::: "memory");   // cur buf landed; 12 in flight
    } else if (it == 30) {
      asm volatile("s_waitcnt vmcnt(6)" ::: "memory");
    } else {
      asm volatile("s_waitcnt vmcnt(0)" ::: "memory");
    }
    __builtin_amdgcn_s_barrier();
    __builtin_amdgcn_sched_barrier(0);
    const short* lA = lds + cb * 12288;
    const short* lB = lA + 4096;
#pragma unroll
    for (int kk = 0; kk < 2; ++kk) {
      int ko = kk ? koff1 : koff0;
      short8 afr[4];
#pragma unroll
      for (int m = 0; m < 4; ++m)
        afr[m] = *(const short8*)(lA + (m * 16 + (lane & 15)) * 64 + ko);
#pragma unroll
      for (int n = 0; n < 2; ++n) {
        short8 bfr = *(const short8*)(lB + (w * 32 + n * 16 + (lane & 15)) * 64 + ko);
#pragma unroll
        for (int m = 0; m < 4; ++m)
          acc[m][n] = __builtin_amdgcn_mfma_f32_16x16x32_bf16(afr[m], bfr, acc[m][n], 0, 0, 0);
      }
    }
    __builtin_amdgcn_s_barrier();
    cb = (cb == 2) ? 0 : cb + 1;
    sb = (sb == 2) ? 0 : sb + 1;
  }
#undef STAGE_SC

  // ---- epilogue: bf16 store + per-row (max, sum-exp) partials over this 128-s tile
  int hi = lane >> 4, cc = lane & 15;
  __syncthreads();
  float2* msred = (float2*)lds;          // [64 j_local][4 w]
#pragma unroll
  for (int m = 0; m < 4; ++m) {
#pragma unroll
    for (int i = 0; i < 4; ++i) {
      int j = j0 + m * 16 + hi * 4 + i;
      float v[2];
#pragma unroll
      for (int n = 0; n < 2; ++n) {
        unsigned short u = f2bf(acc[m][n][i]);
        scores[((size_t)(b * 256 + j)) * 4096 + s0 + w * 32 + n * 16 + cc] = (short)u;
        v[n] = bf2f(u);
      }
      float mx = fmaxf(v[0], v[1]);
#pragma unroll
      for (int o = 1; o < 16; o <<= 1) mx = fmaxf(mx, __shfl_xor(mx, o));
      float sm = __expf(v[0] - mx) + __expf(v[1] - mx);
#pragma unroll
      for (int o = 1; o < 16; o <<= 1) sm += __shfl_xor(sm, o);
      if (cc == 0) msred[(m * 16 + hi * 4 + i) * 4 + w] = make_float2(mx, sm);
    }
  }
  __syncthreads();
  if (t < 64) {
    float2 p0 = msred[t * 4 + 0], p1 = msred[t * 4 + 1];
    float2 p2 = msred[t * 4 + 2], p3 = msred[t * 4 + 3];
    float M = fmaxf(fmaxf(p0.x, p1.x), fmaxf(p2.x, p3.x));
    float S = p0.y * __expf(p0.x - M) + p1.y * __expf(p1.x - M)
            + p2.y * __expf(p2.x - M) + p3.y * __expf(p3.x - M);
    ((float2*)part_ms)[((size_t)(b * 256 + j0 + t)) * 32 + blockIdx.x] = make_float2(M, S);
  }
}

// ---------------------------------------------------------------- fused msum + pbar + h contraction (e-half per block):
// Tpart[sp*128 + b*16 + hh][e] = sum_{s in chunk} pbar[hh][s] * h[s][e]
__global__ __launch_bounds__(256) void k_pt(const short* scores, const float* part_ms,
                                            const short* h, float* Tpart) {
  int sp = blockIdx.x;                      // 0..31 (s-chunks of 128)
  int b  = blockIdx.y;                      // 0..7
  int eh = blockIdx.z;                      // 0..1 (e-halves of 1024)
  int t  = threadIdx.x;
  __shared__ short sc[256 * 128];           // scores chunk [j][s], 64 KB
  __shared__ float lp[16 * 128];            // pbar [h][s], 8 KB
  __shared__ float lms[512];                // per-row (max, inv16sum), 2 KB
  { // per-row softmax combine over 32 tile-partials (row r = t of this b)
    const float2* p = ((const float2*)part_ms) + (size_t)(b * 256 + t) * 32;
    float M = -1e30f;
#pragma unroll
    for (int i = 0; i < 32; ++i) M = fmaxf(M, p[i].x);
    float S = 0.f;
#pragma unroll
    for (int i = 0; i < 32; ++i) S += p[i].y * __expf(p[i].x - M);
    lms[t * 2] = M; lms[t * 2 + 1] = 1.0f / (16.0f * S);
  }
#pragma unroll
  for (int rr = 0; rr < 2; ++rr) {          // stage scores [256 j][128 s]
    int j = rr * 128 + (t >> 1);
    const short8* src = (const short8*)(scores + ((size_t)(b * 256 + j)) * 4096 + sp * 128 + (t & 1) * 64);
    short8* dst = (short8*)(sc + j * 128 + (t & 1) * 64);
#pragma unroll
    for (int i = 0; i < 8; ++i) dst[i] = src[i];
  }
  __syncthreads();
  {
    int s = t & 127, hg = (t >> 7) * 8;
    for (int hh = hg; hh < hg + 8; ++hh) {
      float accp = 0.f;
#pragma unroll
      for (int l = 0; l < 16; ++l) {
        int r = hh * 16 + l;
        accp += __expf(bf2f((unsigned short)sc[r * 128 + s]) - lms[r * 2]) * lms[r * 2 + 1];
      }
      lp[hh * 128 + s] = accp;
    }
  }
  __syncthreads();
  f32x4 a[16];
#pragma unroll
  for (int hh = 0; hh < 16; ++hh) a[hh] = (f32x4){0.f, 0.f, 0.f, 0.f};
  int e0 = eh * 1024 + t * 4;
  const short* hb = h + ((size_t)(b * 4096 + sp * 128)) * 2048 + e0;
  for (int si = 0; si < 128; ++si) {
    short4 hv4 = *(const short4*)(hb + (size_t)si * 2048);
    float hv[4];
    hv[0] = bf2f((unsigned short)hv4.x); hv[1] = bf2f((unsigned short)hv4.y);
    hv[2] = bf2f((unsigned short)hv4.z); hv[3] = bf2f((unsigned short)hv4.w);
#pragma unroll
    for (int hh = 0; hh < 16; ++hh) {
      float p = lp[hh * 128 + si];
#pragma unroll
      for (int c = 0; c < 4; ++c) a[hh][c] += p * hv[c];
    }
  }
#pragma unroll
  for (int hh = 0; hh < 16; ++hh)
    *(f32x4*)(Tpart + ((size_t)(sp * 128 + b * 16 + hh)) * 2048 + e0) = a[hh];
}

// ---------------------------------------------------------------- cbar partials (folds Tpart reduce): part[ey][b][c]
__global__ __launch_bounds__(256) void k_cbar_part(const float* Tpart, const float* w_v, float* part) {
  int t  = threadIdx.x;
  int c  = blockIdx.x * 256 + t;
  int e0 = blockIdx.y * 64;
  __shared__ float tb[2][8][64];            // Tbar slice for this block's 2 h values
  {
    int idx = t * 4;
    int hl = idx >> 9, b = (idx >> 6) & 7, ee = idx & 63;
    int hg = blockIdx.x * 2 + hl;
    f32x4 s = {0.f, 0.f, 0.f, 0.f};
    for (int sp = 0; sp < 32; ++sp) {
      f32x4 v = *(const f32x4*)(Tpart + ((size_t)(sp * 128 + b * 16 + hg)) * 2048 + e0 + ee);
      s += v;
    }
    *(f32x4*)&tb[hl][b][ee] = s;
  }
  __syncthreads();
  int h1 = t >> 7;
  float acc[8];
#pragma unroll
  for (int b = 0; b < 8; ++b) acc[b] = 0.f;
  for (int e = 0; e < 64; ++e) {
    float wv = w_v[(size_t)(e0 + e) * 2048 + c];
#pragma unroll
    for (int b = 0; b < 8; ++b) acc[b] += tb[h1][b][e] * wv;
  }
#pragma unroll
  for (int b = 0; b < 8; ++b) part[((size_t)blockIdx.y * 8 + b) * 2048 + c] = acc[b];
}

// ---------------------------------------------------------------- vecmat partials (folds previous reduce + bias)
__global__ __launch_bounds__(256) void k_vecmat_part(const float* partin, const float* bias,
                                                     const float* W, float* partout) {
  int t  = threadIdx.x;
  int c  = blockIdx.x * 256 + t;
  int e0 = blockIdx.y * 64;
  __shared__ float vin[8][64];
  {
#pragma unroll
    for (int k = 0; k < 2; ++k) {
      int idx = t * 2 + k;
      int b = idx >> 6, ee = idx & 63;
      float s = bias[e0 + ee];
      for (int p = 0; p < 32; ++p) s += partin[((size_t)p * 8 + b) * 2048 + e0 + ee];
      vin[b][ee] = s;
    }
  }
  __syncthreads();
  float acc[8];
#pragma unroll
  for (int b = 0; b < 8; ++b) acc[b] = 0.f;
  for (int e = 0; e < 64; ++e) {
    float wv = W[(size_t)(e0 + e) * 2048 + c];
#pragma unroll
    for (int b = 0; b < 8; ++b) acc[b] += vin[b][e] * wv;
  }
#pragma unroll
  for (int b = 0; b < 8; ++b) partout[((size_t)blockIdx.y * 8 + b) * 2048 + c] = acc[b];
}

// ---------------------------------------------------------------- out = x + broadcast(outv)   (fp32)
__global__ __launch_bounds__(256) void k_resid(const float* x, const float* outv, float* out) {
  size_t i4 = (size_t)blockIdx.x * 256 + threadIdx.x;
  size_t total4 = (size_t)ROWS * 512;
  size_t stride = (size_t)gridDim.x * 256;
  for (; i4 < total4; i4 += stride) {
    int b  = (int)(i4 >> 21);               // 4096*512 float4 per batch
    int c4 = (int)(i4 & 511);
    float4 xv = ((const float4*)x)[i4];
    float4 ov = ((const float4*)outv)[b * 512 + c4];
    float4 o;
    o.x = xv.x + ov.x; o.y = xv.y + ov.y;
    o.z = xv.z + ov.z; o.w = xv.w + ov.w;
    ((float4*)out)[i4] = o;
  }
}

// ================================================================ launch
extern "C" void kernel_launch(void* const* d_in, const int* in_sizes, int n_in,
                              void* d_out, int out_size, void* d_ws, size_t ws_size,
                              hipStream_t stream) {
  const float* x       = (const float*)d_in[0];
  const float* ln_g    = (const float*)d_in[1];
  const float* ln_b    = (const float*)d_in[2];
  const float* latents = (const float*)d_in[3];
  const float* w_lq    = (const float*)d_in[4];
  const float* b_lq    = (const float*)d_in[5];
  const float* w_k     = (const float*)d_in[6];
  // const float* b_k  = (const float*)d_in[7];   // softmax-invariant, unused
  const float* w_v     = (const float*)d_in[8];
  const float* b_v     = (const float*)d_in[9];
  const float* w_lv    = (const float*)d_in[10];
  const float* b_lv    = (const float*)d_in[11];
  const float* w_out   = (const float*)d_in[12];
  const float* b_out   = (const float*)d_in[13];

  // d_out is fp32 [8,4096,2048] = 268 MB; first ~195 MB doubles as scratch, no overlaps,
  // all dead before k_resid (which reads only x and outv) overwrites the full buffer.
  char* base = (char*)d_out;
  short* scores  = (short*)(base);                       //  16,777,216 B (bf16)
  short* h       = (short*)(base + 16777216);            // 134,217,728 B (bf16 LN(x))
  float* Tpart   = (float*)(base + 150994944);           //  33,554,432 B
  float* part_ms = (float*)(base + 184549376);           //     524,288 B (32 tiles/row now)
  float* q       = (float*)(base + 185073664);           //     131,072 B
  short* wq_t    = (short*)(base + 185204736);           //   1,048,576 B
  float* qpart   = (float*)(base + 186253312);           //   4,194,304 B
  float* part    = (float*)(base + 190447616);           //   2,097,152 B
  float* part2   = (float*)(base + 192544768);           //   2,097,152 B
  float* outv    = (float*)d_ws;                         //      65,536 B (ws_size >= 64 KB proven)
  float* out     = (float*)d_out;

  k_q_part     <<<dim3(8, 32), 256, 0, stream>>>(latents, w_lq, qpart);
  k_reduce     <<<dim3(8, 16), 256, 0, stream>>>(qpart, b_lq, q, 16);
  k_lnT        <<<32768, 256, 0, stream>>>(x, ln_g, ln_b, h);
  k_wq         <<<2048, 256, 0, stream>>>(w_k, q, wq_t);
  k_scores     <<<dim3(32, 4, 8), 256, 0, stream>>>(h, wq_t, scores, part_ms);
  k_pt         <<<dim3(32, 8, 2), 256, 0, stream>>>(scores, part_ms, h, Tpart);
  k_cbar_part  <<<dim3(8, 32), 256, 0, stream>>>(Tpart, w_v, part);
  k_vecmat_part<<<dim3(8, 32), 256, 0, stream>>>(part, b_v, w_lv, part2);
  k_vecmat_part<<<dim3(8, 32), 256, 0, stream>>>(part2, b_lv, w_out, part);
  k_reduce     <<<dim3(8, 8), 256, 0, stream>>>(part, b_out, outv, 8);
  k_resid      <<<2048, 256, 0, stream>>>(x, outv, out);
}